// Round 10
// baseline (91.187 us; speedup 1.0000x reference)
//
#include <hip/hip_runtime.h>

#define NPRED 1445
#define NCLS  80
#define MAXDET 300
#define OUTC  86
#define CONF_T 0.6f
#define IOU_T  0.45f
#define MAX_WH 4096.0f
#define HWSZ  289
#define NIMG  32
#define SLOTS 768      // ws slots per image (M mean ~396, sigma ~17)
#define MCAP  512      // fast-path cap (~7 sigma)
#define NWP   8        // words per suppression row in GLOBAL supMat
#define SMS   9        // LDS smat row stride in u64 (8 words + 1 pad)

// ---- d_ws layout (bytes) ----
#define OFF_KEPT 128        // int[32]
#define OFF_KEY  256        // u64[32][SLOTS]  (after sort_kernel: rank-sorted)
#define OFF_BOX  196864     // float4[32][SLOTS]   (unsorted, by slot)
#define OFF_DST  590080     // int[32][MAXDET]     (RANK per kept output row)
#define OFF_SBOX 726784     // float4[32][SLOTS]   (rank-sorted boxes)
#define OFF_SUP  1120000    // u64[32][MCAP][NWP]  (suppression bitmask rows)
#define WS_FULL  2168576

__device__ __forceinline__ unsigned long long bcast64(unsigned long long v, int srcLane) {
    unsigned lo = (unsigned)__builtin_amdgcn_readlane((int)(unsigned)(v & 0xFFFFFFFFULL), srcLane);
    unsigned hi = (unsigned)__builtin_amdgcn_readlane((int)(unsigned)(v >> 32), srcLane);
    return ((unsigned long long)hi << 32) | lo;
}

// ================= kernel 0: zero the counters =================
__global__ __launch_bounds__(64)
void zero_kernel(int* __restrict__ wsCnt) {
    wsCnt[threadIdx.x] = 0;        // covers wsCnt[32] + wsKept[32] (contiguous)
}

// ================= kernel 1: per-candidate prep =================
__global__ __launch_bounds__(128)
void prep_kernel(const float* __restrict__ score, int* __restrict__ wsCnt,
                 unsigned long long* __restrict__ wsKey, float4* __restrict__ wsBox) {
    const int b = blockIdx.x;
    const int ci = blockIdx.y * 128 + threadIdx.x;
    if (ci >= NPRED) return;
    const int t5 = ci / HWSZ;
    const int hw = ci - t5 * HWSZ;
    const int n = hw * 5 + t5;                     // candidate row in x[N][85]
    const float* base = score + (size_t)b * 425 * HWSZ + (size_t)(t5 * 85) * HWSZ + hw;
    float x = base[0];
    float y = base[HWSZ];
    float w = base[2 * HWSZ];
    float h = base[3 * HWSZ];
    float obj = base[4 * HWSZ];

    float best = -INFINITY; int bj = 0;
    #pragma unroll 16
    for (int k = 0; k < NCLS; ++k) {
        float v = base[(5 + k) * HWSZ] * obj;      // cls = logits * obj
        if (v > best) { best = v; bj = k; }        // strict >: first-occurrence argmax
    }
    if (!((obj > CONF_T) && (best > CONF_T))) return;

    float wh2 = w * 0.5f, hh2 = h * 0.5f;
    float x1 = x - wh2, y1 = y - hh2, x2 = x + wh2, y2 = y + hh2;
    float off = (float)bj * MAX_WH;                // exact product
    int slot = atomicAdd(&wsCnt[b], 1);
    if (slot >= SLOTS) return;
    unsigned int u = __float_as_uint(best);        // conf > 0.6 -> positive
    unsigned int desc = ~(u | 0x80000000u);        // ascending u64 == descending conf
    wsKey[b * SLOTS + slot] = ((unsigned long long)desc << 32)
                            | ((unsigned long long)(unsigned)n << 16)
                            | ((unsigned long long)(unsigned)bj << 8);
    wsBox[b * SLOTS + slot] = make_float4(x1 + off, y1 + off, x2 + off, y2 + off);
}

// ================= kernel 2: rank-count sort (in-place key permute) =================
__global__ __launch_bounds__(1024)
void sort_kernel(const int* __restrict__ wsCnt, unsigned long long* __restrict__ wsKey,
                 const float4* __restrict__ wsBox, float4* __restrict__ wsSBox) {
    __shared__ unsigned long long keys[SLOTS];
    const int b = blockIdx.x, tid = threadIdx.x;
    int M = wsCnt[b]; if (M > SLOTS) M = SLOTS;
    for (int i = tid; i < M; i += 1024) keys[i] = wsKey[b * SLOTS + i];
    __syncthreads();
    if (tid < M) {                                 // M <= 768 < 1024: one key/thread
        unsigned long long ki = keys[tid];
        int rank = 0;
        #pragma unroll 4
        for (int j = 0; j < M; ++j) rank += (keys[j] < ki) ? 1 : 0;   // unique keys
        wsKey[b * SLOTS + rank] = ki;              // rank-sorted keys (LDS snapshot safe)
        wsSBox[b * SLOTS + rank] = wsBox[b * SLOTS + tid];
    }
}

// ================= kernel 3: suppression bitmask matrix (global, 256 blocks) =========
__global__ __launch_bounds__(512)
void supmat_kernel(const int* __restrict__ wsCnt, const float4* __restrict__ wsSBox,
                   unsigned long long* __restrict__ supMat) {
    const int b = blockIdx.x, w = blockIdx.y, tid = threadIdx.x;
    int M = wsCnt[b]; if (M > SLOTS) M = SLOTS;
    if (M > MCAP) return;                          // fallback path handles
    __shared__ float4 box[MCAP];
    for (int r = tid; r < M; r += 512) box[r] = wsSBox[b * SLOTS + r];
    __syncthreads();
    const int lane = tid & 63, wid = tid >> 6;
    const int j = (w << 6) + lane;
    float4 jb = make_float4(0.f, 0.f, 0.f, 0.f); float ab = 0.f;
    const bool jok = (j < M);
    if (jok) { jb = box[j]; ab = (jb.z - jb.x) * (jb.w - jb.y); }
    unsigned long long* rowBase = supMat + ((size_t)b * MCAP) * NWP + w;
    if (wid >= M) return;
    float4 nxt = box[wid];
    for (int i = wid; i < M; i += 8) {
        float4 cur = nxt;
        int nx = i + 8; if (nx < M) nxt = box[nx];   // depth-1 prefetch
        float aa = (cur.z - cur.x) * (cur.w - cur.y);
        bool sup = false;
        if (jok && j > i) {
            float ltx = fmaxf(cur.x, jb.x), lty = fmaxf(cur.y, jb.y);
            float rbx = fminf(cur.z, jb.z), rby = fminf(cur.w, jb.w);
            float ww = fmaxf(rbx - ltx, 0.0f), hh = fmaxf(rby - lty, 0.0f);
            float inter = ww * hh;
            float denom = ((aa + ab) - inter) + 1e-9f;   // left-to-right, exact div
            sup = (inter / denom) > IOU_T;
        }
        unsigned long long mask = __ballot(sup);
        if (lane == 0) rowBase[(size_t)i * NWP] = mask;  // every (i<M, w<8) written
    }
}

// ================= kernel 4: greedy scan — register rows + shuffle-butterfly ==========
struct ScanSh {
    union {
        unsigned long long smat[MCAP * SMS];       // fast path: 36 KB staged matrix
        struct {
            float x1[SLOTS], y1[SLOTS], x2[SLOTS], y2[SLOTS];
            unsigned char kp[SLOTS];
        } fb;                                       // fallback arrays (~13 KB)
    } u;
};

__global__ __launch_bounds__(256)
void scan_kernel(const int* __restrict__ wsCnt, const unsigned long long* __restrict__ supMat,
                 const float4* __restrict__ wsSBox,
                 int* __restrict__ wsKept, int* __restrict__ wsDst) {
    __shared__ ScanSh sh;
    const int b = blockIdx.x, tid = threadIdx.x;
    int M = wsCnt[b]; if (M > SLOTS) M = SLOTS;

    if (M <= MCAP) {
        // ---- parallel stage: global supMat slice -> LDS (coalesced, re-strided) ----
        const unsigned long long* rows = supMat + ((size_t)b * MCAP) * NWP;
        const int total = M * NWP;
        for (int t = tid; t < total; t += 256)
            sh.u.smat[(t >> 3) * SMS + (t & 7)] = rows[t];
        __syncthreads();
        if (tid >= 64) return;                      // single wave below; no barriers
        const int lane = tid;
        const int NW = (M + 63) >> 6;

        // ---- keep-state in uniform registers ----
        unsigned long long Kr[8];
        #pragma unroll
        for (int w = 0; w < 8; ++w) {
            int rem = M - (w << 6);
            Kr[w] = (rem >= 64) ? ~0ULL : ((rem > 0) ? ((~0ULL) >> (64 - rem)) : 0ULL);
        }

        // ---- forward substitution over 64-row word-blocks ----
        for (int w2 = 0; w2 < NW; ++w2) {
            const int row = (w2 << 6) + lane;
            // lane i holds row (64*w2+i)'s words in REGISTERS (independent ds_reads)
            unsigned long long R[8];
            #pragma unroll
            for (int w = 0; w < 8; ++w)
                R[w] = (w >= w2 && w < NW && row < M) ? sh.u.smat[row * SMS + w] : 0ULL;

            // intra-block resolve: uniform serial bit-walk (the irreducible greedy core)
            unsigned long long cur = Kr[w2];
            unsigned long long scratch = cur;
            while (scratch) {
                int i = __ffsll((long long)scratch) - 1;
                scratch &= scratch - 1;
                if ((cur >> i) & 1ULL)              // still kept -> suppress within block
                    cur &= ~bcast64(R[w2], i);      // diag bits j<=i are 0: keeps i
            }
            Kr[w2] = cur;

            // inter-block bulk suppression: OR of kept rows' words via shfl butterfly
            if (w2 + 1 < NW) {
                const bool keptLane = ((cur >> lane) & 1ULL) != 0ULL;
                #pragma unroll
                for (int l = 0; l < 8; ++l) {
                    if (l <= w2 || l >= NW) continue;
                    unsigned long long v = keptLane ? R[l] : 0ULL;
                    #pragma unroll
                    for (int m = 1; m < 64; m <<= 1)
                        v |= __shfl_xor(v, m, 64);  // log-depth OR-reduce, uniform result
                    Kr[l] &= ~v;
                }
            }
        }

        // ---- compaction: popcount prefix in registers, 64-lane parallel stores ----
        int pre[9]; pre[0] = 0;
        #pragma unroll
        for (int w = 0; w < 8; ++w) pre[w + 1] = pre[w] + __popcll(Kr[w]);
        if (lane == 0) wsKept[b] = (pre[8] < MAXDET) ? pre[8] : MAXDET;
        #pragma unroll
        for (int w = 0; w < 8; ++w) {
            if (w >= NW) break;
            unsigned long long kw = Kr[w];
            if ((kw >> lane) & 1ULL) {
                int rank = pre[w] + __popcll(kw & ((1ULL << lane) - 1ULL));
                if (rank < MAXDET) wsDst[b * MAXDET + rank] = (w << 6) + lane; // RANK
            }
        }
    } else {
        // ---- fallback (M > MCAP, ~0 probability): barrier-serial greedy ----
        for (int r = tid; r < M; r += 256) {
            float4 v = wsSBox[b * SLOTS + r];
            sh.u.fb.x1[r] = v.x; sh.u.fb.y1[r] = v.y;
            sh.u.fb.x2[r] = v.z; sh.u.fb.y2[r] = v.w; sh.u.fb.kp[r] = 1;
        }
        __syncthreads();
        for (int i = 0; i < M; ++i) {
            if (sh.u.fb.kp[i]) {
                float ax1 = sh.u.fb.x1[i], ay1 = sh.u.fb.y1[i];
                float ax2 = sh.u.fb.x2[i], ay2 = sh.u.fb.y2[i];
                float aa = (ax2 - ax1) * (ay2 - ay1);
                for (int r = i + 1 + tid; r < M; r += 256) {
                    float bx1 = sh.u.fb.x1[r], by1 = sh.u.fb.y1[r];
                    float bx2 = sh.u.fb.x2[r], by2 = sh.u.fb.y2[r];
                    float ab = (bx2 - bx1) * (by2 - by1);
                    float ltx = fmaxf(ax1, bx1), lty = fmaxf(ay1, by1);
                    float rbx = fminf(ax2, bx2), rby = fminf(ay2, by2);
                    float ww = fmaxf(rbx - ltx, 0.0f), hh = fmaxf(rby - lty, 0.0f);
                    float inter = ww * hh;
                    float denom = ((aa + ab) - inter) + 1e-9f;
                    if ((inter / denom) > IOU_T) sh.u.fb.kp[r] = 0;
                }
            }
            __syncthreads();
        }
        if (tid == 0) {
            int c2 = 0;
            for (int r = 0; r < M && c2 < MAXDET; ++r)
                if (sh.u.fb.kp[r]) wsDst[b * MAXDET + c2++] = r;    // store RANK
            wsKept[b] = c2;
        }
    }
}

// ================= kernel 5: output write =================
__global__ __launch_bounds__(256)
void out_kernel(const float* __restrict__ score, const int* __restrict__ wsKept,
                const unsigned long long* __restrict__ wsKey,   // rank-sorted
                const int* __restrict__ wsDst, float* __restrict__ out) {
    const int b = blockIdx.x;
    const int e = blockIdx.y * 256 + threadIdx.x;
    if (e >= MAXDET * OUTC) return;
    const int row = e / OUTC, c = e - row * OUTC;
    float v = 0.0f;
    if (row < wsKept[b]) {
        unsigned long long key = wsKey[b * SLOTS + wsDst[b * MAXDET + row]];
        int n = (int)((key >> 16) & 0xFFFFULL);
        int cls = (int)((key >> 8) & 0xFFULL);
        int hw = n / 5, t5 = n - hw * 5;
        const float* base = score + (size_t)b * 425 * HWSZ + (size_t)(t5 * 85) * HWSZ + hw;
        if (c < 4) {
            float x = base[0];
            float y = base[HWSZ];
            float w = base[2 * HWSZ];
            float h = base[3 * HWSZ];
            float wh2 = w * 0.5f, hh2 = h * 0.5f;
            v = (c == 0) ? (x - wh2) : (c == 1) ? (y - hh2)
              : (c == 2) ? (x + wh2) : (y + hh2);
        } else if (c == 4) {
            v = __uint_as_float((~(unsigned int)(key >> 32)) & 0x7FFFFFFFu);
        } else if (c == 5) {
            v = (float)cls;
        } else {
            v = base[(c - 1) * HWSZ];              // raw logits
        }
    }
    out[(size_t)b * MAXDET * OUTC + e] = v;
}

// ================= last-resort fallback: round-2 single kernel (proven) =================
struct SMemFB {
    float bx1[NPRED], by1[NPRED], bx2[NPRED], by2[NPRED], area[NPRED];
    unsigned short sortedN[NPRED];
    union {
        unsigned long long vkey[NPRED];
        struct { float confR[MAXDET]; unsigned char jclsR[MAXDET]; } oi;
        unsigned char keepFB[NPRED];
    } u;
    unsigned short dstN[MAXDET];
    int validCount;
    int keptCount;
};

__device__ __forceinline__ void conf_argmax(const float* __restrict__ base, float obj,
                                            float& conf, int& bj) {
    float best = -INFINITY; int bjj = 0;
    #pragma unroll 8
    for (int k = 0; k < NCLS; ++k) {
        float v = base[(5 + k) * HWSZ] * obj;
        if (v > best) { best = v; bjj = k; }
    }
    conf = best; bj = bjj;
}

__global__ __launch_bounds__(1024)
void yolo_nms_single(const float* __restrict__ score, float* __restrict__ out) {
    __shared__ SMemFB s;
    const int b = blockIdx.x;
    const int tid = threadIdx.x;
    const float* sb = score + (size_t)b * 425 * HWSZ;
    if (tid == 0) s.validCount = 0;
    __syncthreads();
    for (int ci = tid; ci < NPRED; ci += 1024) {
        int t5 = ci / HWSZ;
        int hw = ci - t5 * HWSZ;
        int n = hw * 5 + t5;
        const float* base = sb + (size_t)(t5 * 85) * HWSZ + hw;
        float x = base[0], y = base[HWSZ], w = base[2 * HWSZ], h = base[3 * HWSZ];
        float obj = base[4 * HWSZ];
        float conf; int bj;
        conf_argmax(base, obj, conf, bj);
        bool valid = (obj > CONF_T) && (conf > CONF_T);
        float wh2 = w * 0.5f, hh2 = h * 0.5f;
        float x1 = x - wh2, y1 = y - hh2, x2 = x + wh2, y2 = y + hh2;
        float off = (float)bj * MAX_WH;
        float ox1 = x1 + off, oy1 = y1 + off, ox2 = x2 + off, oy2 = y2 + off;
        s.bx1[n] = ox1; s.by1[n] = oy1; s.bx2[n] = ox2; s.by2[n] = oy2;
        s.area[n] = (ox2 - ox1) * (oy2 - oy1);
        if (valid) {
            int slot = atomicAdd(&s.validCount, 1);
            unsigned int uu = __float_as_uint(conf);
            unsigned int desc = ~(uu | 0x80000000u);
            s.u.vkey[slot] = ((unsigned long long)desc << 32) | (unsigned int)n;
        }
    }
    __syncthreads();
    const int M = s.validCount;
    for (int vi = tid; vi < M; vi += 1024) {
        unsigned long long ki = s.u.vkey[vi];
        int rank = 0;
        for (int j = 0; j < M; ++j) rank += (s.u.vkey[j] < ki) ? 1 : 0;
        s.sortedN[rank] = (unsigned short)(ki & 0xFFFFULL);
    }
    __syncthreads();
    for (int r = tid; r < M; r += 1024) s.u.keepFB[r] = 1;
    __syncthreads();
    for (int i = 0; i < M; ++i) {
        if (s.u.keepFB[i]) {
            int ni = s.sortedN[i];
            float ax1 = s.bx1[ni], ay1 = s.by1[ni], ax2 = s.bx2[ni], ay2 = s.by2[ni];
            float aa = s.area[ni];
            for (int r = i + 1 + tid; r < M; r += 1024) {
                int nj = s.sortedN[r];
                float ltx = fmaxf(ax1, s.bx1[nj]);
                float lty = fmaxf(ay1, s.by1[nj]);
                float rbx = fminf(ax2, s.bx2[nj]);
                float rby = fminf(ay2, s.by2[nj]);
                float ww = fmaxf(rbx - ltx, 0.0f);
                float hh = fmaxf(rby - lty, 0.0f);
                float inter = ww * hh;
                float denom = ((aa + s.area[nj]) - inter) + 1e-9f;
                if ((inter / denom) > IOU_T) s.u.keepFB[r] = 0;
            }
        }
        __syncthreads();
    }
    if (tid == 0) {
        int cnt = 0;
        for (int r = 0; r < M && cnt < MAXDET; ++r)
            if (s.u.keepFB[r]) s.dstN[cnt++] = s.sortedN[r];
        s.keptCount = cnt;
    }
    __syncthreads();
    const int cnt = s.keptCount;
    if (tid < cnt) {
        int n = s.dstN[tid];
        int hw = n / 5, t5 = n - hw * 5;
        const float* base = sb + (size_t)(t5 * 85) * HWSZ + hw;
        float obj = base[4 * HWSZ];
        float conf; int bj;
        conf_argmax(base, obj, conf, bj);
        s.u.oi.confR[tid] = conf;
        s.u.oi.jclsR[tid] = (unsigned char)bj;
    }
    __syncthreads();
    float* ob = out + (size_t)b * MAXDET * OUTC;
    for (int e = tid; e < MAXDET * OUTC; e += 1024) {
        int row = e / OUTC, c = e - row * OUTC;
        float v = 0.0f;
        if (row < cnt) {
            int n = s.dstN[row];
            int hw = n / 5, t5 = n - hw * 5;
            const float* base = sb + (size_t)(t5 * 85) * HWSZ + hw;
            if (c < 4) {
                float x = base[0], y = base[HWSZ], w = base[2 * HWSZ], h = base[3 * HWSZ];
                float wh2 = w * 0.5f, hh2 = h * 0.5f;
                v = (c == 0) ? (x - wh2) : (c == 1) ? (y - hh2)
                  : (c == 2) ? (x + wh2) : (y + hh2);
            } else if (c == 4) {
                v = s.u.oi.confR[row];
            } else if (c == 5) {
                v = (float)s.u.oi.jclsR[row];
            } else {
                v = base[(c - 1) * HWSZ];
            }
        }
        ob[e] = v;
    }
}

extern "C" void kernel_launch(void* const* d_in, const int* in_sizes, int n_in,
                              void* d_out, int out_size, void* d_ws, size_t ws_size,
                              hipStream_t stream) {
    const float* score = (const float*)d_in[0];
    float* out = (float*)d_out;
    char* ws = (char*)d_ws;
    int* wsCnt = (int*)ws;
    int* wsKept = (int*)(ws + OFF_KEPT);
    unsigned long long* wsKey = (unsigned long long*)(ws + OFF_KEY);
    float4* wsBox = (float4*)(ws + OFF_BOX);
    int* wsDst = (int*)(ws + OFF_DST);
    float4* wsSBox = (float4*)(ws + OFF_SBOX);
    unsigned long long* supMat = (unsigned long long*)(ws + OFF_SUP);

    if (ws_size >= (size_t)WS_FULL) {
        zero_kernel<<<1, 64, 0, stream>>>(wsCnt);   // zeroes wsCnt[32]+wsKept[32]
        prep_kernel<<<dim3(NIMG, 12), 128, 0, stream>>>(score, wsCnt, wsKey, wsBox);
        sort_kernel<<<NIMG, 1024, 0, stream>>>(wsCnt, wsKey, wsBox, wsSBox);
        supmat_kernel<<<dim3(NIMG, NWP), 512, 0, stream>>>(wsCnt, wsSBox, supMat);
        scan_kernel<<<NIMG, 256, 0, stream>>>(wsCnt, supMat, wsSBox, wsKept, wsDst);
        out_kernel<<<dim3(NIMG, 101), 256, 0, stream>>>(score, wsKept, wsKey, wsDst, out);
    } else {
        yolo_nms_single<<<NIMG, 1024, 0, stream>>>(score, out);
    }
}

// Round 11
// 55.859 us; speedup vs baseline: 1.6325x; 1.6325x over previous
//
#include <hip/hip_runtime.h>

#define NPRED 1445
#define NCLS  80
#define MAXDET 300
#define OUTC  86
#define CONF_T 0.6f
#define IOU_T  0.45f
#define MAX_WH 4096.0f
#define HWSZ  289
#define NIMG  32
#define SLOTS 768      // ws slots per image (M mean ~396, sigma ~17)
#define MCAP  512      // fast-path cap (~7 sigma)
#define NWP   8        // words per suppression row in GLOBAL supMat
#define SMS   9        // LDS smat row stride in u64 (8 words + 1 pad)
#define ECAP  4096     // edge-walk cap (expected E ~ 10-100)

// ---- d_ws layout (bytes) ----
#define OFF_KEPT 128        // int[32]
#define OFF_KEY  256        // u64[32][SLOTS]  (after sort_kernel: rank-sorted)
#define OFF_BOX  196864     // float4[32][SLOTS]   (unsorted, by slot)
#define OFF_DST  590080     // int[32][MAXDET]     (RANK per kept output row)
#define OFF_SBOX 726784     // float4[32][SLOTS]   (rank-sorted boxes)
#define OFF_SUP  1120000    // u64[32][MCAP][NWP]  (suppression bitmask rows)
#define WS_FULL  2168576

__device__ __forceinline__ unsigned long long bcast64(unsigned long long v, int srcLane) {
    unsigned lo = (unsigned)__builtin_amdgcn_readlane((int)(unsigned)(v & 0xFFFFFFFFULL), srcLane);
    unsigned hi = (unsigned)__builtin_amdgcn_readlane((int)(unsigned)(v >> 32), srcLane);
    return ((unsigned long long)hi << 32) | lo;
}

// ================= kernel 0: zero the counters =================
__global__ __launch_bounds__(64)
void zero_kernel(int* __restrict__ wsCnt) {
    wsCnt[threadIdx.x] = 0;        // covers wsCnt[32] + wsKept[32] (contiguous)
}

// ================= kernel 1: per-candidate prep =================
__global__ __launch_bounds__(128)
void prep_kernel(const float* __restrict__ score, int* __restrict__ wsCnt,
                 unsigned long long* __restrict__ wsKey, float4* __restrict__ wsBox) {
    const int b = blockIdx.x;
    const int ci = blockIdx.y * 128 + threadIdx.x;
    if (ci >= NPRED) return;
    const int t5 = ci / HWSZ;
    const int hw = ci - t5 * HWSZ;
    const int n = hw * 5 + t5;                     // candidate row in x[N][85]
    const float* base = score + (size_t)b * 425 * HWSZ + (size_t)(t5 * 85) * HWSZ + hw;
    float x = base[0];
    float y = base[HWSZ];
    float w = base[2 * HWSZ];
    float h = base[3 * HWSZ];
    float obj = base[4 * HWSZ];

    float best = -INFINITY; int bj = 0;
    #pragma unroll 16
    for (int k = 0; k < NCLS; ++k) {
        float v = base[(5 + k) * HWSZ] * obj;      // cls = logits * obj
        if (v > best) { best = v; bj = k; }        // strict >: first-occurrence argmax
    }
    if (!((obj > CONF_T) && (best > CONF_T))) return;

    float wh2 = w * 0.5f, hh2 = h * 0.5f;
    float x1 = x - wh2, y1 = y - hh2, x2 = x + wh2, y2 = y + hh2;
    float off = (float)bj * MAX_WH;                // exact product
    int slot = atomicAdd(&wsCnt[b], 1);
    if (slot >= SLOTS) return;
    unsigned int u = __float_as_uint(best);        // conf > 0.6 -> positive
    unsigned int desc = ~(u | 0x80000000u);        // ascending u64 == descending conf
    wsKey[b * SLOTS + slot] = ((unsigned long long)desc << 32)
                            | ((unsigned long long)(unsigned)n << 16)
                            | ((unsigned long long)(unsigned)bj << 8);
    wsBox[b * SLOTS + slot] = make_float4(x1 + off, y1 + off, x2 + off, y2 + off);
}

// ================= kernel 2: rank-count sort (in-place key permute) =================
__global__ __launch_bounds__(1024)
void sort_kernel(const int* __restrict__ wsCnt, unsigned long long* __restrict__ wsKey,
                 const float4* __restrict__ wsBox, float4* __restrict__ wsSBox) {
    __shared__ unsigned long long keys[SLOTS];
    const int b = blockIdx.x, tid = threadIdx.x;
    int M = wsCnt[b]; if (M > SLOTS) M = SLOTS;
    for (int i = tid; i < M; i += 1024) keys[i] = wsKey[b * SLOTS + i];
    __syncthreads();
    if (tid < M) {                                 // M <= 768 < 1024: one key/thread
        unsigned long long ki = keys[tid];
        int rank = 0;
        #pragma unroll 4
        for (int j = 0; j < M; ++j) rank += (keys[j] < ki) ? 1 : 0;   // unique keys
        wsKey[b * SLOTS + rank] = ki;              // rank-sorted keys (LDS snapshot safe)
        wsSBox[b * SLOTS + rank] = wsBox[b * SLOTS + tid];
    }
}

// ================= kernel 3: suppression bitmask matrix (global, 256 blocks) =========
__global__ __launch_bounds__(512)
void supmat_kernel(const int* __restrict__ wsCnt, const float4* __restrict__ wsSBox,
                   unsigned long long* __restrict__ supMat) {
    const int b = blockIdx.x, w = blockIdx.y, tid = threadIdx.x;
    int M = wsCnt[b]; if (M > SLOTS) M = SLOTS;
    if (M > MCAP) return;                          // fallback path handles
    __shared__ float4 box[MCAP];
    for (int r = tid; r < M; r += 512) box[r] = wsSBox[b * SLOTS + r];
    __syncthreads();
    const int lane = tid & 63, wid = tid >> 6;
    const int j = (w << 6) + lane;
    float4 jb = make_float4(0.f, 0.f, 0.f, 0.f); float ab = 0.f;
    const bool jok = (j < M);
    if (jok) { jb = box[j]; ab = (jb.z - jb.x) * (jb.w - jb.y); }
    unsigned long long* rowBase = supMat + ((size_t)b * MCAP) * NWP + w;
    if (wid >= M) return;
    float4 nxt = box[wid];
    for (int i = wid; i < M; i += 8) {
        float4 cur = nxt;
        int nx = i + 8; if (nx < M) nxt = box[nx];   // depth-1 prefetch
        float aa = (cur.z - cur.x) * (cur.w - cur.y);
        bool sup = false;
        if (jok && j > i) {
            float ltx = fmaxf(cur.x, jb.x), lty = fmaxf(cur.y, jb.y);
            float rbx = fminf(cur.z, jb.z), rby = fminf(cur.w, jb.w);
            float ww = fmaxf(rbx - ltx, 0.0f), hh = fmaxf(rby - lty, 0.0f);
            float inter = ww * hh;
            float denom = ((aa + ab) - inter) + 1e-9f;   // left-to-right, exact div
            sup = (inter / denom) > IOU_T;
        }
        unsigned long long mask = __ballot(sup);
        if (lane == 0) rowBase[(size_t)i * NWP] = mask;  // every (i<M, w<8) written
    }
}

// ================= kernel 4: greedy scan — sparse edge extraction + walk ==============
struct ScanSh {
    union {
        unsigned long long smat[MCAP * SMS];       // 36864 B staged matrix
        struct {
            float x1[SLOTS], y1[SLOTS], x2[SLOTS], y2[SLOTS];
            unsigned char kp[SLOTS];
        } fb;                                       // fallback arrays (~13 KB)
    } u;
    unsigned int edges[ECAP];                      // 16384 B (sorted (i<<9|j))
    int wtot[4];
};

__global__ __launch_bounds__(256)
void scan_kernel(const int* __restrict__ wsCnt, const unsigned long long* __restrict__ supMat,
                 const float4* __restrict__ wsSBox,
                 int* __restrict__ wsKept, int* __restrict__ wsDst) {
    __shared__ ScanSh sh;
    const int b = blockIdx.x, tid = threadIdx.x;
    const int lane = tid & 63, wid = tid >> 6;
    int M = wsCnt[b]; if (M > SLOTS) M = SLOTS;

    if (M <= MCAP) {
        // ---- stage: global supMat slice -> LDS (coalesced, re-strided) ----
        const unsigned long long* rows = supMat + ((size_t)b * MCAP) * NWP;
        const int total = M * NWP;
        for (int t = tid; t < total; t += 256)
            sh.u.smat[(t >> 3) * SMS + (t & 7)] = rows[t];
        __syncthreads();

        // ---- popcount + prefix-sum over contiguous chunks (deterministic order) ----
        const int K = (total + 255) >> 8;
        int t0 = tid * K, t1 = t0 + K;
        if (t0 > total) t0 = total;
        if (t1 > total) t1 = total;
        int cnt = 0;
        for (int t = t0; t < t1; ++t) cnt += __popcll(sh.u.smat[(t >> 3) * SMS + (t & 7)]);
        int inc = cnt;
        #pragma unroll
        for (int m = 1; m < 64; m <<= 1) {
            int v = __shfl_up(inc, m, 64);
            if (lane >= m) inc += v;
        }
        if (lane == 63) sh.wtot[wid] = inc;
        __syncthreads();
        int base = 0;
        for (int w = 0; w < wid; ++w) base += sh.wtot[w];
        int slot = base + inc - cnt;               // exclusive global prefix
        const int Etot = sh.wtot[0] + sh.wtot[1] + sh.wtot[2] + sh.wtot[3];

        if (Etot <= ECAP) {
            // ---- extract set bits as (i<<9|j), globally sorted by construction ----
            for (int t = t0; t < t1; ++t) {
                unsigned long long wv = sh.u.smat[(t >> 3) * SMS + (t & 7)];
                unsigned int i9 = (unsigned)(t >> 3) << 9;
                unsigned int jw = (unsigned)(t & 7) << 6;
                while (wv) {
                    int bit = __ffsll((long long)wv) - 1;
                    wv &= wv - 1;
                    sh.edges[slot++] = i9 | (jw + (unsigned)bit);
                }
            }
            __syncthreads();
            if (tid >= 64) return;                  // single wave below
            // ---- edge walk: lane l owns keep word l ----
            unsigned long long Kw = 0ULL;
            { int rem = M - (lane << 6);
              if (rem >= 64) Kw = ~0ULL; else if (rem > 0) Kw = (~0ULL) >> (64 - rem); }
            unsigned int A[8], B[8];
#define LOADE(buf, bs) { _Pragma("unroll") for (int k = 0; k < 8; ++k) { \
            int e2 = (bs) + k; buf[k] = (e2 < Etot) ? sh.edges[e2] : 0xFFFFFFFFu; } }
#define PROCE(buf) { _Pragma("unroll") for (int k = 0; k < 8; ++k) { \
            unsigned int ek = buf[k]; \
            if (ek != 0xFFFFFFFFu) { \
                int ei = (int)(ek >> 9), ej = (int)(ek & 511u); \
                unsigned long long kwi = bcast64(Kw, ei >> 6); \
                if ((kwi >> (ei & 63)) & 1ULL) { \
                    if (lane == (ej >> 6)) Kw &= ~(1ULL << (ej & 63)); \
                } } } }
            LOADE(A, 0)
            for (int e = 0; e < Etot; e += 16) {
                LOADE(B, e + 8)
                PROCE(A)
                LOADE(A, e + 16)
                PROCE(B)
            }
#undef LOADE
#undef PROCE
            // ---- compaction: lane-parallel popcount prefix ----
            int myc = __popcll(Kw);
            int incc = myc;
            #pragma unroll
            for (int m = 1; m < 64; m <<= 1) {
                int v = __shfl_up(incc, m, 64);
                if (lane >= m) incc += v;
            }
            int tot = __shfl(incc, 63, 64);
            if (lane == 0) wsKept[b] = (tot < MAXDET) ? tot : MAXDET;
            int r = incc - myc;                     // exclusive prefix
            unsigned long long kw = Kw;
            while (kw) {
                int i = __ffsll((long long)kw) - 1;
                kw &= kw - 1;
                if (r < MAXDET) wsDst[b * MAXDET + r] = (lane << 6) + i;  // RANK
                ++r;
            }
        } else {
            // ---- dense fallback (E > ECAP): proven single-wave bit-scan ----
            if (tid >= 64) return;
            unsigned long long keepW = 0ULL;
            { int rem = M - (lane << 6);
              if (rem >= 64) keepW = ~0ULL; else if (rem > 0) keepW = (~0ULL) >> (64 - rem); }
            const bool ld = (lane < NWP);
            unsigned long long A2[8], B2[8];
            int cnt2 = 0; bool done = false;
#define LOADB(buf, bs) { _Pragma("unroll") for (int k = 0; k < 8; ++k) { \
            int ii = (bs) + k; buf[k] = (ld && ii < M) ? sh.u.smat[ii * SMS + lane] : 0ULL; } }
#define PROCB(buf, bs) { _Pragma("unroll") for (int k = 0; k < 8; ++k) { \
            int ii = (bs) + k; \
            if (!done && ii < M) { \
                unsigned long long w64 = bcast64(keepW, ii >> 6); \
                if ((w64 >> (ii & 63)) & 1ULL) { \
                    keepW &= ~buf[k]; \
                    if (lane == 0) wsDst[b * MAXDET + cnt2] = ii; \
                    ++cnt2; \
                    if (cnt2 == MAXDET) done = true; \
                } } } }
            LOADB(A2, 0)
            for (int base2 = 0; base2 < M && !done; base2 += 16) {
                LOADB(B2, base2 + 8)
                PROCB(A2, base2)
                LOADB(A2, base2 + 16)
                PROCB(B2, base2 + 8)
            }
#undef LOADB
#undef PROCB
            if (lane == 0) wsKept[b] = cnt2;
        }
    } else {
        // ---- fallback (M > MCAP, ~0 probability): barrier-serial greedy ----
        for (int r = tid; r < M; r += 256) {
            float4 v = wsSBox[b * SLOTS + r];
            sh.u.fb.x1[r] = v.x; sh.u.fb.y1[r] = v.y;
            sh.u.fb.x2[r] = v.z; sh.u.fb.y2[r] = v.w; sh.u.fb.kp[r] = 1;
        }
        __syncthreads();
        for (int i = 0; i < M; ++i) {
            if (sh.u.fb.kp[i]) {
                float ax1 = sh.u.fb.x1[i], ay1 = sh.u.fb.y1[i];
                float ax2 = sh.u.fb.x2[i], ay2 = sh.u.fb.y2[i];
                float aa = (ax2 - ax1) * (ay2 - ay1);
                for (int r = i + 1 + tid; r < M; r += 256) {
                    float bx1 = sh.u.fb.x1[r], by1 = sh.u.fb.y1[r];
                    float bx2 = sh.u.fb.x2[r], by2 = sh.u.fb.y2[r];
                    float ab = (bx2 - bx1) * (by2 - by1);
                    float ltx = fmaxf(ax1, bx1), lty = fmaxf(ay1, by1);
                    float rbx = fminf(ax2, bx2), rby = fminf(ay2, by2);
                    float ww = fmaxf(rbx - ltx, 0.0f), hh = fmaxf(rby - lty, 0.0f);
                    float inter = ww * hh;
                    float denom = ((aa + ab) - inter) + 1e-9f;
                    if ((inter / denom) > IOU_T) sh.u.fb.kp[r] = 0;
                }
            }
            __syncthreads();
        }
        if (tid == 0) {
            int c2 = 0;
            for (int r = 0; r < M && c2 < MAXDET; ++r)
                if (sh.u.fb.kp[r]) wsDst[b * MAXDET + c2++] = r;    // store RANK
            wsKept[b] = c2;
        }
    }
}

// ================= kernel 5: output write =================
__global__ __launch_bounds__(256)
void out_kernel(const float* __restrict__ score, const int* __restrict__ wsKept,
                const unsigned long long* __restrict__ wsKey,   // rank-sorted
                const int* __restrict__ wsDst, float* __restrict__ out) {
    const int b = blockIdx.x;
    const int e = blockIdx.y * 256 + threadIdx.x;
    if (e >= MAXDET * OUTC) return;
    const int row = e / OUTC, c = e - row * OUTC;
    float v = 0.0f;
    if (row < wsKept[b]) {
        unsigned long long key = wsKey[b * SLOTS + wsDst[b * MAXDET + row]];
        int n = (int)((key >> 16) & 0xFFFFULL);
        int cls = (int)((key >> 8) & 0xFFULL);
        int hw = n / 5, t5 = n - hw * 5;
        const float* base = score + (size_t)b * 425 * HWSZ + (size_t)(t5 * 85) * HWSZ + hw;
        if (c < 4) {
            float x = base[0];
            float y = base[HWSZ];
            float w = base[2 * HWSZ];
            float h = base[3 * HWSZ];
            float wh2 = w * 0.5f, hh2 = h * 0.5f;
            v = (c == 0) ? (x - wh2) : (c == 1) ? (y - hh2)
              : (c == 2) ? (x + wh2) : (y + hh2);
        } else if (c == 4) {
            v = __uint_as_float((~(unsigned int)(key >> 32)) & 0x7FFFFFFFu);
        } else if (c == 5) {
            v = (float)cls;
        } else {
            v = base[(c - 1) * HWSZ];              // raw logits
        }
    }
    out[(size_t)b * MAXDET * OUTC + e] = v;
}

// ================= last-resort fallback: round-2 single kernel (proven) =================
struct SMemFB {
    float bx1[NPRED], by1[NPRED], bx2[NPRED], by2[NPRED], area[NPRED];
    unsigned short sortedN[NPRED];
    union {
        unsigned long long vkey[NPRED];
        struct { float confR[MAXDET]; unsigned char jclsR[MAXDET]; } oi;
        unsigned char keepFB[NPRED];
    } u;
    unsigned short dstN[MAXDET];
    int validCount;
    int keptCount;
};

__device__ __forceinline__ void conf_argmax(const float* __restrict__ base, float obj,
                                            float& conf, int& bj) {
    float best = -INFINITY; int bjj = 0;
    #pragma unroll 8
    for (int k = 0; k < NCLS; ++k) {
        float v = base[(5 + k) * HWSZ] * obj;
        if (v > best) { best = v; bjj = k; }
    }
    conf = best; bj = bjj;
}

__global__ __launch_bounds__(1024)
void yolo_nms_single(const float* __restrict__ score, float* __restrict__ out) {
    __shared__ SMemFB s;
    const int b = blockIdx.x;
    const int tid = threadIdx.x;
    const float* sb = score + (size_t)b * 425 * HWSZ;
    if (tid == 0) s.validCount = 0;
    __syncthreads();
    for (int ci = tid; ci < NPRED; ci += 1024) {
        int t5 = ci / HWSZ;
        int hw = ci - t5 * HWSZ;
        int n = hw * 5 + t5;
        const float* base = sb + (size_t)(t5 * 85) * HWSZ + hw;
        float x = base[0], y = base[HWSZ], w = base[2 * HWSZ], h = base[3 * HWSZ];
        float obj = base[4 * HWSZ];
        float conf; int bj;
        conf_argmax(base, obj, conf, bj);
        bool valid = (obj > CONF_T) && (conf > CONF_T);
        float wh2 = w * 0.5f, hh2 = h * 0.5f;
        float x1 = x - wh2, y1 = y - hh2, x2 = x + wh2, y2 = y + hh2;
        float off = (float)bj * MAX_WH;
        float ox1 = x1 + off, oy1 = y1 + off, ox2 = x2 + off, oy2 = y2 + off;
        s.bx1[n] = ox1; s.by1[n] = oy1; s.bx2[n] = ox2; s.by2[n] = oy2;
        s.area[n] = (ox2 - ox1) * (oy2 - oy1);
        if (valid) {
            int slot = atomicAdd(&s.validCount, 1);
            unsigned int uu = __float_as_uint(conf);
            unsigned int desc = ~(uu | 0x80000000u);
            s.u.vkey[slot] = ((unsigned long long)desc << 32) | (unsigned int)n;
        }
    }
    __syncthreads();
    const int M = s.validCount;
    for (int vi = tid; vi < M; vi += 1024) {
        unsigned long long ki = s.u.vkey[vi];
        int rank = 0;
        for (int j = 0; j < M; ++j) rank += (s.u.vkey[j] < ki) ? 1 : 0;
        s.sortedN[rank] = (unsigned short)(ki & 0xFFFFULL);
    }
    __syncthreads();
    for (int r = tid; r < M; r += 1024) s.u.keepFB[r] = 1;
    __syncthreads();
    for (int i = 0; i < M; ++i) {
        if (s.u.keepFB[i]) {
            int ni = s.sortedN[i];
            float ax1 = s.bx1[ni], ay1 = s.by1[ni], ax2 = s.bx2[ni], ay2 = s.by2[ni];
            float aa = s.area[ni];
            for (int r = i + 1 + tid; r < M; r += 1024) {
                int nj = s.sortedN[r];
                float ltx = fmaxf(ax1, s.bx1[nj]);
                float lty = fmaxf(ay1, s.by1[nj]);
                float rbx = fminf(ax2, s.bx2[nj]);
                float rby = fminf(ay2, s.by2[nj]);
                float ww = fmaxf(rbx - ltx, 0.0f);
                float hh = fmaxf(rby - lty, 0.0f);
                float inter = ww * hh;
                float denom = ((aa + s.area[nj]) - inter) + 1e-9f;
                if ((inter / denom) > IOU_T) s.u.keepFB[r] = 0;
            }
        }
        __syncthreads();
    }
    if (tid == 0) {
        int cnt = 0;
        for (int r = 0; r < M && cnt < MAXDET; ++r)
            if (s.u.keepFB[r]) s.dstN[cnt++] = s.sortedN[r];
        s.keptCount = cnt;
    }
    __syncthreads();
    const int cnt = s.keptCount;
    if (tid < cnt) {
        int n = s.dstN[tid];
        int hw = n / 5, t5 = n - hw * 5;
        const float* base = sb + (size_t)(t5 * 85) * HWSZ + hw;
        float obj = base[4 * HWSZ];
        float conf; int bj;
        conf_argmax(base, obj, conf, bj);
        s.u.oi.confR[tid] = conf;
        s.u.oi.jclsR[tid] = (unsigned char)bj;
    }
    __syncthreads();
    float* ob = out + (size_t)b * MAXDET * OUTC;
    for (int e = tid; e < MAXDET * OUTC; e += 1024) {
        int row = e / OUTC, c = e - row * OUTC;
        float v = 0.0f;
        if (row < cnt) {
            int n = s.dstN[row];
            int hw = n / 5, t5 = n - hw * 5;
            const float* base = sb + (size_t)(t5 * 85) * HWSZ + hw;
            if (c < 4) {
                float x = base[0], y = base[HWSZ], w = base[2 * HWSZ], h = base[3 * HWSZ];
                float wh2 = w * 0.5f, hh2 = h * 0.5f;
                v = (c == 0) ? (x - wh2) : (c == 1) ? (y - hh2)
                  : (c == 2) ? (x + wh2) : (y + hh2);
            } else if (c == 4) {
                v = s.u.oi.confR[row];
            } else if (c == 5) {
                v = (float)s.u.oi.jclsR[row];
            } else {
                v = base[(c - 1) * HWSZ];
            }
        }
        ob[e] = v;
    }
}

extern "C" void kernel_launch(void* const* d_in, const int* in_sizes, int n_in,
                              void* d_out, int out_size, void* d_ws, size_t ws_size,
                              hipStream_t stream) {
    const float* score = (const float*)d_in[0];
    float* out = (float*)d_out;
    char* ws = (char*)d_ws;
    int* wsCnt = (int*)ws;
    int* wsKept = (int*)(ws + OFF_KEPT);
    unsigned long long* wsKey = (unsigned long long*)(ws + OFF_KEY);
    float4* wsBox = (float4*)(ws + OFF_BOX);
    int* wsDst = (int*)(ws + OFF_DST);
    float4* wsSBox = (float4*)(ws + OFF_SBOX);
    unsigned long long* supMat = (unsigned long long*)(ws + OFF_SUP);

    if (ws_size >= (size_t)WS_FULL) {
        zero_kernel<<<1, 64, 0, stream>>>(wsCnt);   // zeroes wsCnt[32]+wsKept[32]
        prep_kernel<<<dim3(NIMG, 12), 128, 0, stream>>>(score, wsCnt, wsKey, wsBox);
        sort_kernel<<<NIMG, 1024, 0, stream>>>(wsCnt, wsKey, wsBox, wsSBox);
        supmat_kernel<<<dim3(NIMG, NWP), 512, 0, stream>>>(wsCnt, wsSBox, supMat);
        scan_kernel<<<NIMG, 256, 0, stream>>>(wsCnt, supMat, wsSBox, wsKept, wsDst);
        out_kernel<<<dim3(NIMG, 101), 256, 0, stream>>>(score, wsKept, wsKey, wsDst, out);
    } else {
        yolo_nms_single<<<NIMG, 1024, 0, stream>>>(score, out);
    }
}

// Round 12
// 45.845 us; speedup vs baseline: 1.9890x; 1.2184x over previous
//
#include <hip/hip_runtime.h>

#define NPRED 1445
#define RAWSTR 1472    // padded per-image stride for raw arrays
#define NCLS  80
#define MAXDET 300
#define OUTC  86
#define CONF_T 0.6f
#define IOU_T  0.45f
#define MAX_WH 4096.0f
#define HWSZ  289
#define NIMG  32
#define SLOTS 768      // compacted slots per image (M mean ~396, sigma ~17)
#define MCAP  512      // edge fast-path cap (~7 sigma)
#define EPB   256      // edge capacity per (image, j-word) region
#define EWALK 2048     // 8*EPB: max edges the walk path handles

// ---- d_ws layout (bytes); total 2,022,144 < proven-available 2,168,576 ----
#define OFF_CNT  128        // int[32]   M per image (written by sort)
#define OFF_KEYR 256        // u64[32][RAWSTR]  raw keys by candidate (sentinel ~0)
#define OFF_BOXR 377088     // float4[32][RAWSTR] raw offset boxes by candidate
#define OFF_KEY  1130752    // u64[32][SLOTS]   rank-sorted keys
#define OFF_SBOX 1327360    // float4[32][SLOTS] rank-sorted boxes
#define OFF_ECNT 1720576    // int[32][8]       per-region edge counts
#define OFF_EDG  1721600    // u32[32][8][EPB]  edges (i<<9|j), unsorted
#define OFF_DST  1983744    // int[32][MAXDET]  RANK per kept output row
#define WS_NEED  2022144
// wsKept = int[32] at offset 0

__device__ __forceinline__ unsigned long long bcast64(unsigned long long v, int srcLane) {
    unsigned lo = (unsigned)__builtin_amdgcn_readlane((int)(unsigned)(v & 0xFFFFFFFFULL), srcLane);
    unsigned hi = (unsigned)__builtin_amdgcn_readlane((int)(unsigned)(v >> 32), srcLane);
    return ((unsigned long long)hi << 32) | lo;
}

// ================= kernel 1: per-candidate prep (deterministic slots, no atomics) =====
__global__ __launch_bounds__(128)
void prep_kernel(const float* __restrict__ score, unsigned long long* __restrict__ wsKeyRaw,
                 float4* __restrict__ wsBoxRaw) {
    const int b = blockIdx.x;
    const int ci = blockIdx.y * 128 + threadIdx.x;
    if (ci >= NPRED) return;
    const int t5 = ci / HWSZ;
    const int hw = ci - t5 * HWSZ;
    const int n = hw * 5 + t5;                     // candidate row in x[N][85]
    const float* base = score + (size_t)b * 425 * HWSZ + (size_t)(t5 * 85) * HWSZ + hw;
    float x = base[0];
    float y = base[HWSZ];
    float w = base[2 * HWSZ];
    float h = base[3 * HWSZ];
    float obj = base[4 * HWSZ];

    float best = -INFINITY; int bj = 0;
    #pragma unroll 16
    for (int k = 0; k < NCLS; ++k) {
        float v = base[(5 + k) * HWSZ] * obj;      // cls = logits * obj
        if (v > best) { best = v; bj = k; }        // strict >: first-occurrence argmax
    }

    float wh2 = w * 0.5f, hh2 = h * 0.5f;
    float x1 = x - wh2, y1 = y - hh2, x2 = x + wh2, y2 = y + hh2;
    float off = (float)bj * MAX_WH;                // exact product

    unsigned long long key = ~0ULL;                // invalid sentinel (MSB set)
    if ((obj > CONF_T) && (best > CONF_T)) {
        unsigned int u = __float_as_uint(best);    // conf > 0.6 -> positive, MSB 0
        unsigned int desc = ~(u | 0x80000000u);    // ascending u64 == descending conf
        key = ((unsigned long long)desc << 32)
            | ((unsigned long long)(unsigned)n << 16)
            | ((unsigned long long)(unsigned)bj << 8);
    }
    wsKeyRaw[b * RAWSTR + ci] = key;
    wsBoxRaw[b * RAWSTR + ci] = make_float4(x1 + off, y1 + off, x2 + off, y2 + off);
}

// ================= kernel 2: compact (prefix-sum) + rank-count sort ==================
__global__ __launch_bounds__(1024)
void sort_kernel(const unsigned long long* __restrict__ wsKeyRaw,
                 const float4* __restrict__ wsBoxRaw,
                 int* __restrict__ wsCnt, unsigned long long* __restrict__ wsKey,
                 float4* __restrict__ wsSBox) {
    __shared__ unsigned long long keys[NPRED];
    __shared__ unsigned long long ckeys[SLOTS];
    __shared__ unsigned short cidx[SLOTS];
    __shared__ int wtot[16];
    __shared__ int mTot;
    const int b = blockIdx.x, tid = threadIdx.x;
    const int lane = tid & 63, wid = tid >> 6;

    for (int i = tid; i < NPRED; i += 1024) keys[i] = wsKeyRaw[b * RAWSTR + i];
    __syncthreads();

    // validity prefix-sum: thread owns elems {tid, tid+1024}; order irrelevant (sorted next)
    const int i0 = tid, i1 = tid + 1024;
    const bool v0 = (keys[i0] >> 63) == 0ULL;                 // valid keys have MSB 0
    const bool v1 = (i1 < NPRED) && ((keys[i1] >> 63) == 0ULL);
    int cnt = (int)v0 + (int)v1;
    int inc = cnt;
    #pragma unroll
    for (int m = 1; m < 64; m <<= 1) {
        int v = __shfl_up(inc, m, 64);
        if (lane >= m) inc += v;
    }
    if (lane == 63) wtot[wid] = inc;
    __syncthreads();
    int basep = 0;
    for (int w = 0; w < wid; ++w) basep += wtot[w];
    int pos = basep + inc - cnt;                              // exclusive global prefix
    if (v0 && pos < SLOTS) cidx[pos] = (unsigned short)i0;
    if (v1 && pos + (int)v0 < SLOTS) cidx[pos + (int)v0] = (unsigned short)i1;
    if (tid == 0) {
        int t = 0;
        for (int w = 0; w < 16; ++w) t += wtot[w];
        mTot = t;
    }
    __syncthreads();
    int M = mTot; if (M > SLOTS) M = SLOTS;
    if (tid == 0) wsCnt[b] = M;
    if (tid < M) ckeys[tid] = keys[cidx[tid]];                // densify (M <= 768 < 1024)
    __syncthreads();
    if (tid < M) {
        unsigned long long ki = ckeys[tid];
        int rank = 0;
        #pragma unroll 4
        for (int j = 0; j < M; ++j) rank += (ckeys[j] < ki) ? 1 : 0;   // unique keys
        wsKey[b * SLOTS + rank] = ki;
        wsSBox[b * SLOTS + rank] = wsBoxRaw[b * RAWSTR + cidx[tid]];
    }
}

// ================= kernel 3: IoU edges (no matrix), 256 blocks ========================
__global__ __launch_bounds__(512)
void edge_kernel(const int* __restrict__ wsCnt, const float4* __restrict__ wsSBox,
                 int* __restrict__ wsECnt, unsigned int* __restrict__ wsEdges) {
    __shared__ float4 box[MCAP];
    __shared__ int ecnt;
    const int b = blockIdx.x, w = blockIdx.y, tid = threadIdx.x;
    int M = wsCnt[b]; if (M > SLOTS) M = SLOTS;
    if (M > MCAP) { if (tid == 0) wsECnt[b * 8 + w] = 0x7FFFFFFF; return; }
    if (tid == 0) ecnt = 0;
    for (int r = tid; r < M; r += 512) box[r] = wsSBox[b * SLOTS + r];
    __syncthreads();
    const int lane = tid & 63, wid = tid >> 6;
    const int j = (w << 6) + lane;
    float4 jb = make_float4(0.f, 0.f, 0.f, 0.f); float ab = 0.f;
    const bool jok = (j < M);
    if (jok) { jb = box[j]; ab = (jb.z - jb.x) * (jb.w - jb.y); }
    unsigned int* reg = wsEdges + (size_t)(b * 8 + w) * EPB;
    for (int i = wid; i < M; i += 8) {
        float4 cur = box[i];
        float aa = (cur.z - cur.x) * (cur.w - cur.y);
        bool sup = false;
        if (jok && j > i) {
            float ltx = fmaxf(cur.x, jb.x), lty = fmaxf(cur.y, jb.y);
            float rbx = fminf(cur.z, jb.z), rby = fminf(cur.w, jb.w);
            float ww = fmaxf(rbx - ltx, 0.0f), hh = fmaxf(rby - lty, 0.0f);
            float inter = ww * hh;
            float denom = ((aa + ab) - inter) + 1e-9f;   // left-to-right, exact div
            sup = (inter / denom) > IOU_T;
        }
        unsigned long long mask = __ballot(sup);
        if (lane == 0 && mask) {
            int pc = __popcll(mask);
            int eb = atomicAdd(&ecnt, pc);               // LDS atomic, block-local
            int k = 0;
            while (mask) {
                int bit = __ffsll((long long)mask) - 1;
                mask &= mask - 1;
                int p = eb + k;
                if (p < EPB) reg[p] = ((unsigned)i << 9) | (unsigned)((w << 6) + bit);
                ++k;
            }
        }
    }
    __syncthreads();
    if (tid == 0) wsECnt[b * 8 + w] = ecnt;              // > EPB signals overflow
}

// ================= kernel 4: edge sort + single-wave greedy walk ======================
struct ScanSh {
    union {
        struct {
            float x1[SLOTS], y1[SLOTS], x2[SLOTS], y2[SLOTS];
            unsigned char kp[SLOTS];
        } fb;                                             // fallback arrays (~13 KB)
        struct { unsigned int eraw[EWALK]; unsigned int esrt[EWALK]; } e; // 16 KB
    } u;
    int ec[8];
    int eoff[9];
    int over;
};

__global__ __launch_bounds__(256)
void scan_kernel(const int* __restrict__ wsCnt, const int* __restrict__ wsECnt,
                 const unsigned int* __restrict__ wsEdges, const float4* __restrict__ wsSBox,
                 int* __restrict__ wsKept, int* __restrict__ wsDst) {
    __shared__ ScanSh sh;
    const int b = blockIdx.x, tid = threadIdx.x, lane = tid & 63;
    int M = wsCnt[b]; if (M > SLOTS) M = SLOTS;
    if (tid < 8) sh.ec[tid] = wsECnt[b * 8 + tid];
    if (tid == 0) sh.over = 0;
    __syncthreads();
    if (tid == 0) {
        int o = 0;
        for (int w = 0; w < 8; ++w) {
            sh.eoff[w] = o;
            int c = sh.ec[w];
            if (c > EPB) { sh.over = 1; c = EPB; }
            o += c;
        }
        sh.eoff[8] = o;
    }
    __syncthreads();
    const bool fast = (M <= MCAP) && (sh.over == 0);
    const int Etot = sh.eoff[8];

    if (fast) {
        // ---- gather edges from 8 regions into LDS ----
        for (int w = 0; w < 8; ++w) {
            int c = sh.ec[w]; if (c > EPB) c = EPB;
            const unsigned int* reg = wsEdges + (size_t)(b * 8 + w) * EPB;
            for (int e2 = tid; e2 < c; e2 += 256) sh.u.e.eraw[sh.eoff[w] + e2] = reg[e2];
        }
        __syncthreads();
        // ---- rank-count sort (unique (i<<9|j) values) ----
        for (int e2 = tid; e2 < Etot; e2 += 256) {
            unsigned int ke = sh.u.e.eraw[e2];
            int rank = 0;
            for (int j2 = 0; j2 < Etot; ++j2) rank += (sh.u.e.eraw[j2] < ke) ? 1 : 0;
            sh.u.e.esrt[rank] = ke;
        }
        __syncthreads();
        if (tid >= 64) return;                      // single wave below
        // ---- edge walk: lane l owns keep word l (proven round-11 structure) ----
        unsigned long long Kw = 0ULL;
        { int rem = M - (lane << 6);
          if (rem >= 64) Kw = ~0ULL; else if (rem > 0) Kw = (~0ULL) >> (64 - rem); }
        unsigned int A[8], B[8];
#define LOADE(buf, bs) { _Pragma("unroll") for (int k = 0; k < 8; ++k) { \
        int e2 = (bs) + k; buf[k] = (e2 < Etot) ? sh.u.e.esrt[e2] : 0xFFFFFFFFu; } }
#define PROCE(buf) { _Pragma("unroll") for (int k = 0; k < 8; ++k) { \
        unsigned int ek = buf[k]; \
        if (ek != 0xFFFFFFFFu) { \
            int ei = (int)(ek >> 9), ej = (int)(ek & 511u); \
            unsigned long long kwi = bcast64(Kw, ei >> 6); \
            if ((kwi >> (ei & 63)) & 1ULL) { \
                if (lane == (ej >> 6)) Kw &= ~(1ULL << (ej & 63)); \
            } } } }
        LOADE(A, 0)
        for (int e = 0; e < Etot; e += 16) {
            LOADE(B, e + 8)
            PROCE(A)
            LOADE(A, e + 16)
            PROCE(B)
        }
#undef LOADE
#undef PROCE
        // ---- compaction: lane-parallel popcount prefix ----
        int myc = __popcll(Kw);
        int incc = myc;
        #pragma unroll
        for (int m = 1; m < 64; m <<= 1) {
            int v = __shfl_up(incc, m, 64);
            if (lane >= m) incc += v;
        }
        int tot = __shfl(incc, 63, 64);
        if (lane == 0) wsKept[b] = (tot < MAXDET) ? tot : MAXDET;
        int r = incc - myc;                         // exclusive prefix
        unsigned long long kw = Kw;
        while (kw) {
            int i = __ffsll((long long)kw) - 1;
            kw &= kw - 1;
            if (r < MAXDET) wsDst[b * MAXDET + r] = (lane << 6) + i;  // RANK
            ++r;
        }
    } else {
        // ---- fallback (M > MCAP or edge overflow, ~0 prob): barrier-serial greedy ----
        for (int r = tid; r < M; r += 256) {
            float4 v = wsSBox[b * SLOTS + r];
            sh.u.fb.x1[r] = v.x; sh.u.fb.y1[r] = v.y;
            sh.u.fb.x2[r] = v.z; sh.u.fb.y2[r] = v.w; sh.u.fb.kp[r] = 1;
        }
        __syncthreads();
        for (int i = 0; i < M; ++i) {
            if (sh.u.fb.kp[i]) {
                float ax1 = sh.u.fb.x1[i], ay1 = sh.u.fb.y1[i];
                float ax2 = sh.u.fb.x2[i], ay2 = sh.u.fb.y2[i];
                float aa = (ax2 - ax1) * (ay2 - ay1);
                for (int r = i + 1 + tid; r < M; r += 256) {
                    float bx1 = sh.u.fb.x1[r], by1 = sh.u.fb.y1[r];
                    float bx2 = sh.u.fb.x2[r], by2 = sh.u.fb.y2[r];
                    float ab = (bx2 - bx1) * (by2 - by1);
                    float ltx = fmaxf(ax1, bx1), lty = fmaxf(ay1, by1);
                    float rbx = fminf(ax2, bx2), rby = fminf(ay2, by2);
                    float ww = fmaxf(rbx - ltx, 0.0f), hh = fmaxf(rby - lty, 0.0f);
                    float inter = ww * hh;
                    float denom = ((aa + ab) - inter) + 1e-9f;
                    if ((inter / denom) > IOU_T) sh.u.fb.kp[r] = 0;
                }
            }
            __syncthreads();
        }
        if (tid == 0) {
            int c2 = 0;
            for (int r = 0; r < M && c2 < MAXDET; ++r)
                if (sh.u.fb.kp[r]) wsDst[b * MAXDET + c2++] = r;    // store RANK
            wsKept[b] = c2;
        }
    }
}

// ================= kernel 5: output write =================
__global__ __launch_bounds__(256)
void out_kernel(const float* __restrict__ score, const int* __restrict__ wsKept,
                const unsigned long long* __restrict__ wsKey,   // rank-sorted
                const int* __restrict__ wsDst, float* __restrict__ out) {
    const int b = blockIdx.x;
    const int e = blockIdx.y * 256 + threadIdx.x;
    if (e >= MAXDET * OUTC) return;
    const int row = e / OUTC, c = e - row * OUTC;
    float v = 0.0f;
    if (row < wsKept[b]) {
        unsigned long long key = wsKey[b * SLOTS + wsDst[b * MAXDET + row]];
        int n = (int)((key >> 16) & 0xFFFFULL);
        int cls = (int)((key >> 8) & 0xFFULL);
        int hw = n / 5, t5 = n - hw * 5;
        const float* base = score + (size_t)b * 425 * HWSZ + (size_t)(t5 * 85) * HWSZ + hw;
        if (c < 4) {
            float x = base[0];
            float y = base[HWSZ];
            float w = base[2 * HWSZ];
            float h = base[3 * HWSZ];
            float wh2 = w * 0.5f, hh2 = h * 0.5f;
            v = (c == 0) ? (x - wh2) : (c == 1) ? (y - hh2)
              : (c == 2) ? (x + wh2) : (y + hh2);
        } else if (c == 4) {
            v = __uint_as_float((~(unsigned int)(key >> 32)) & 0x7FFFFFFFu);
        } else if (c == 5) {
            v = (float)cls;
        } else {
            v = base[(c - 1) * HWSZ];              // raw logits
        }
    }
    out[(size_t)b * MAXDET * OUTC + e] = v;
}

// ================= last-resort fallback: round-2 single kernel (proven) =================
struct SMemFB {
    float bx1[NPRED], by1[NPRED], bx2[NPRED], by2[NPRED], area[NPRED];
    unsigned short sortedN[NPRED];
    union {
        unsigned long long vkey[NPRED];
        struct { float confR[MAXDET]; unsigned char jclsR[MAXDET]; } oi;
        unsigned char keepFB[NPRED];
    } u;
    unsigned short dstN[MAXDET];
    int validCount;
    int keptCount;
};

__device__ __forceinline__ void conf_argmax(const float* __restrict__ base, float obj,
                                            float& conf, int& bj) {
    float best = -INFINITY; int bjj = 0;
    #pragma unroll 8
    for (int k = 0; k < NCLS; ++k) {
        float v = base[(5 + k) * HWSZ] * obj;
        if (v > best) { best = v; bjj = k; }
    }
    conf = best; bj = bjj;
}

__global__ __launch_bounds__(1024)
void yolo_nms_single(const float* __restrict__ score, float* __restrict__ out) {
    __shared__ SMemFB s;
    const int b = blockIdx.x;
    const int tid = threadIdx.x;
    const float* sb = score + (size_t)b * 425 * HWSZ;
    if (tid == 0) s.validCount = 0;
    __syncthreads();
    for (int ci = tid; ci < NPRED; ci += 1024) {
        int t5 = ci / HWSZ;
        int hw = ci - t5 * HWSZ;
        int n = hw * 5 + t5;
        const float* base = sb + (size_t)(t5 * 85) * HWSZ + hw;
        float x = base[0], y = base[HWSZ], w = base[2 * HWSZ], h = base[3 * HWSZ];
        float obj = base[4 * HWSZ];
        float conf; int bj;
        conf_argmax(base, obj, conf, bj);
        bool valid = (obj > CONF_T) && (conf > CONF_T);
        float wh2 = w * 0.5f, hh2 = h * 0.5f;
        float x1 = x - wh2, y1 = y - hh2, x2 = x + wh2, y2 = y + hh2;
        float off = (float)bj * MAX_WH;
        float ox1 = x1 + off, oy1 = y1 + off, ox2 = x2 + off, oy2 = y2 + off;
        s.bx1[n] = ox1; s.by1[n] = oy1; s.bx2[n] = ox2; s.by2[n] = oy2;
        s.area[n] = (ox2 - ox1) * (oy2 - oy1);
        if (valid) {
            int slot = atomicAdd(&s.validCount, 1);
            unsigned int uu = __float_as_uint(conf);
            unsigned int desc = ~(uu | 0x80000000u);
            s.u.vkey[slot] = ((unsigned long long)desc << 32) | (unsigned int)n;
        }
    }
    __syncthreads();
    const int M = s.validCount;
    for (int vi = tid; vi < M; vi += 1024) {
        unsigned long long ki = s.u.vkey[vi];
        int rank = 0;
        for (int j = 0; j < M; ++j) rank += (s.u.vkey[j] < ki) ? 1 : 0;
        s.sortedN[rank] = (unsigned short)(ki & 0xFFFFULL);
    }
    __syncthreads();
    for (int r = tid; r < M; r += 1024) s.u.keepFB[r] = 1;
    __syncthreads();
    for (int i = 0; i < M; ++i) {
        if (s.u.keepFB[i]) {
            int ni = s.sortedN[i];
            float ax1 = s.bx1[ni], ay1 = s.by1[ni], ax2 = s.bx2[ni], ay2 = s.by2[ni];
            float aa = s.area[ni];
            for (int r = i + 1 + tid; r < M; r += 1024) {
                int nj = s.sortedN[r];
                float ltx = fmaxf(ax1, s.bx1[nj]);
                float lty = fmaxf(ay1, s.by1[nj]);
                float rbx = fminf(ax2, s.bx2[nj]);
                float rby = fminf(ay2, s.by2[nj]);
                float ww = fmaxf(rbx - ltx, 0.0f);
                float hh = fmaxf(rby - lty, 0.0f);
                float inter = ww * hh;
                float denom = ((aa + s.area[nj]) - inter) + 1e-9f;
                if ((inter / denom) > IOU_T) s.u.keepFB[r] = 0;
            }
        }
        __syncthreads();
    }
    if (tid == 0) {
        int cnt = 0;
        for (int r = 0; r < M && cnt < MAXDET; ++r)
            if (s.u.keepFB[r]) s.dstN[cnt++] = s.sortedN[r];
        s.keptCount = cnt;
    }
    __syncthreads();
    const int cnt = s.keptCount;
    if (tid < cnt) {
        int n = s.dstN[tid];
        int hw = n / 5, t5 = n - hw * 5;
        const float* base = sb + (size_t)(t5 * 85) * HWSZ + hw;
        float obj = base[4 * HWSZ];
        float conf; int bj;
        conf_argmax(base, obj, conf, bj);
        s.u.oi.confR[tid] = conf;
        s.u.oi.jclsR[tid] = (unsigned char)bj;
    }
    __syncthreads();
    float* ob = out + (size_t)b * MAXDET * OUTC;
    for (int e = tid; e < MAXDET * OUTC; e += 1024) {
        int row = e / OUTC, c = e - row * OUTC;
        float v = 0.0f;
        if (row < cnt) {
            int n = s.dstN[row];
            int hw = n / 5, t5 = n - hw * 5;
            const float* base = sb + (size_t)(t5 * 85) * HWSZ + hw;
            if (c < 4) {
                float x = base[0], y = base[HWSZ], w = base[2 * HWSZ], h = base[3 * HWSZ];
                float wh2 = w * 0.5f, hh2 = h * 0.5f;
                v = (c == 0) ? (x - wh2) : (c == 1) ? (y - hh2)
                  : (c == 2) ? (x + wh2) : (y + hh2);
            } else if (c == 4) {
                v = s.u.oi.confR[row];
            } else if (c == 5) {
                v = (float)s.u.oi.jclsR[row];
            } else {
                v = base[(c - 1) * HWSZ];
            }
        }
        ob[e] = v;
    }
}

extern "C" void kernel_launch(void* const* d_in, const int* in_sizes, int n_in,
                              void* d_out, int out_size, void* d_ws, size_t ws_size,
                              hipStream_t stream) {
    const float* score = (const float*)d_in[0];
    float* out = (float*)d_out;
    char* ws = (char*)d_ws;
    int* wsKept = (int*)ws;
    int* wsCnt  = (int*)(ws + OFF_CNT);
    unsigned long long* wsKeyRaw = (unsigned long long*)(ws + OFF_KEYR);
    float4* wsBoxRaw = (float4*)(ws + OFF_BOXR);
    unsigned long long* wsKey = (unsigned long long*)(ws + OFF_KEY);
    float4* wsSBox = (float4*)(ws + OFF_SBOX);
    int* wsECnt = (int*)(ws + OFF_ECNT);
    unsigned int* wsEdges = (unsigned int*)(ws + OFF_EDG);
    int* wsDst = (int*)(ws + OFF_DST);

    if (ws_size >= (size_t)WS_NEED) {
        prep_kernel<<<dim3(NIMG, 12), 128, 0, stream>>>(score, wsKeyRaw, wsBoxRaw);
        sort_kernel<<<NIMG, 1024, 0, stream>>>(wsKeyRaw, wsBoxRaw, wsCnt, wsKey, wsSBox);
        edge_kernel<<<dim3(NIMG, 8), 512, 0, stream>>>(wsCnt, wsSBox, wsECnt, wsEdges);
        scan_kernel<<<NIMG, 256, 0, stream>>>(wsCnt, wsECnt, wsEdges, wsSBox, wsKept, wsDst);
        out_kernel<<<dim3(NIMG, 101), 256, 0, stream>>>(score, wsKept, wsKey, wsDst, out);
    } else {
        yolo_nms_single<<<NIMG, 1024, 0, stream>>>(score, out);
    }
}